// Round 3
// baseline (165.750 us; speedup 1.0000x reference)
//
#include <hip/hip_runtime.h>

// Laplace attention: N=2, C=512, S=256, fp32.
// weights[n,c,d] = softmax_d( -sum_s |k[n,d,s]-q[n,c,s]| / 2 )
// out[n,c,s] = sum_d weights[n,c,d] * v[n,d,s]
//
// Round-7: single FUSED kernel, no workspace, no combine launch.
// Post-mortem of rounds 5/6: main's window showed FETCH 122MB (= full k/v
// panel refetch by 512 blocks, zero cache reuse after the 256MiB ws-poison
// wiped L2/L3) + 267MB WRITE (= the poison's dirty-line writeback draining
// during our kernel). (122+267)MB / 118us = 3.3 TB/s = observed hbm_gbps:
// the kernel was 100% HBM-bound. Fix = cut FETCH ~10x, stop using ws:
//  - 256 blocks (1/CU), 4 waves; wave w owns q-row c0+w end-to-end.
//  - Online softmax over 8 chunks of 64 d-rows (flash within the block;
//    full d per block -> no split, no workspace, no combine).
//  - k/v chunks staged in LDS (k stride 260 floats: lane-varying-row reads
//    land on rotated banks = inherent-minimum cycles; v/q rows read
//    broadcast/consecutive -> no padding needed). 133 KB LDS, 1 block/CU.
//  - n = b&1: each XCD's 32 blocks share one n's 2MB k/v working set ->
//    L2-resident after first touch. Unique input/n = 2MB -> FETCH ~4-15MB.
//  - k double-buffered through regs; loads issued a phase early so global
//    latency hides under logits/PV compute. 3 barriers per chunk.

constexpr int N_  = 2;
constexpr int C_  = 512;
constexpr int S_  = 256;
constexpr int S4  = S_ / 4;           // 64 float4 per row
constexpr int TC  = 4;                // q rows per block == waves
constexpr int DC  = 64;               // d rows per chunk
constexpr int NCH = C_ / DC;          // 8 chunks
constexpr int KST = S_ + 4;           // k row stride (floats): bank-rotated, 16B-aligned
constexpr int F4C = DC * S4 / 256;    // float4 per thread per chunk stage (=16)

// ---- DPP wave-reduce helpers ----
template <int CTRL, int ROW_MASK>
__device__ __forceinline__ float dpp_add(float x) {
    int yi = __builtin_amdgcn_update_dpp(0, __float_as_int(x), CTRL, ROW_MASK, 0xf, true);
    return x + __int_as_float(yi);
}
template <int CTRL, int ROW_MASK>
__device__ __forceinline__ float dpp_max(float x) {
    int yi = __builtin_amdgcn_update_dpp(__float_as_int(x), __float_as_int(x), CTRL, ROW_MASK, 0xf, false);
    return fmaxf(x, __int_as_float(yi));
}
__device__ __forceinline__ float wave_sum_bcast(float x) {
    x = dpp_add<0x111, 0xf>(x);   // row_shr:1
    x = dpp_add<0x112, 0xf>(x);   // row_shr:2
    x = dpp_add<0x114, 0xf>(x);   // row_shr:4
    x = dpp_add<0x118, 0xf>(x);   // row_shr:8
    x = dpp_add<0x142, 0xa>(x);   // row_bcast15
    x = dpp_add<0x143, 0xc>(x);   // row_bcast31 -> lane63 = total
    return __int_as_float(__builtin_amdgcn_readlane(__float_as_int(x), 63));
}
__device__ __forceinline__ float wave_max_bcast(float x) {
    x = dpp_max<0x111, 0xf>(x);
    x = dpp_max<0x112, 0xf>(x);
    x = dpp_max<0x114, 0xf>(x);
    x = dpp_max<0x118, 0xf>(x);
    x = dpp_max<0x142, 0xa>(x);
    x = dpp_max<0x143, 0xc>(x);
    return __int_as_float(__builtin_amdgcn_readlane(__float_as_int(x), 63));
}

__global__ __launch_bounds__(256, 1)
void laplace_attn_fused(const float* __restrict__ qg,
                        const float* __restrict__ kg,
                        const float* __restrict__ vg,
                        float* __restrict__ out) {
    // LDS: 4*256*4 + 64*260*4 + 64*256*4 = 133 KB (1 block/CU on 160 KB)
    __shared__ __align__(16) float qs[TC][S_];
    __shared__ __align__(16) float ksm[DC][KST];
    __shared__ __align__(16) float vsm[DC][S_];

    const int b    = blockIdx.x;
    const int n    = b & 1;               // XCD parity groups share one n
    const int c0   = (b >> 1) * TC;
    const int tid  = threadIdx.x;
    const int w    = tid >> 6;            // wave = local c-row
    const int lane = tid & 63;            // d (logits) / s-quad (PV, o)

    const float* kn = kg + (size_t)n * C_ * S_;
    const float* vn = vg + (size_t)n * C_ * S_;

    // ---- prologue: issue k-chunk-0 loads, stage q, write k0 ----
    float4 kreg[F4C];
    #pragma unroll
    for (int it = 0; it < F4C; ++it) {
        const int f   = tid + 256 * it;   // 0..4095 float4 slots
        const int row = f >> 6;           // 64 float4 per row
        const int c4  = f & 63;
        kreg[it] = *(const float4*)(kn + (size_t)row * S_ + (c4 << 2));
    }
    {
        const float4 qv = *(const float4*)(qg + ((size_t)n * C_ + c0 + w) * S_ + (lane << 2));
        *(float4*)&qs[w][lane << 2] = qv;
    }
    #pragma unroll
    for (int it = 0; it < F4C; ++it) {
        const int f   = tid + 256 * it;
        const int row = f >> 6;
        const int c4  = f & 63;
        *(float4*)&ksm[row][c4 << 2] = kreg[it];
    }
    __syncthreads();

    float  m_run = -3.402823466e+38f;     // -FLT_MAX (finite: no inf-inf NaN)
    float  l_run = 0.f;
    float4 o = make_float4(0.f, 0.f, 0.f, 0.f);

    for (int ch = 0; ch < NCH; ++ch) {
        const int d0 = ch * DC;

        // 1. issue v_ch global loads (arrive during logits compute)
        float4 vreg[F4C];
        #pragma unroll
        for (int it = 0; it < F4C; ++it) {
            const int f   = tid + 256 * it;
            const int row = f >> 6;
            const int c4  = f & 63;
            vreg[it] = *(const float4*)(vn + (size_t)(d0 + row) * S_ + (c4 << 2));
        }

        // 2. logits: lane d, wave c -> dist = sum_s |k[d][s]-q[c][s]|
        float dist = 0.f;
        #pragma unroll
        for (int s4 = 0; s4 < S4; ++s4) {
            const float4 kf = *(const float4*)&ksm[lane][s4 << 2]; // rotated banks
            const float4 qf = *(const float4*)&qs[w][s4 << 2];     // broadcast
            dist += (fabsf(kf.x - qf.x) + fabsf(kf.y - qf.y))
                  + (fabsf(kf.z - qf.z) + fabsf(kf.w - qf.w));
        }

        // 3. online-softmax update (register-only, per wave)
        const float x     = -0.5f * dist;
        const float Mc    = wave_max_bcast(x);
        const float m_new = fmaxf(m_run, Mc);
        const float aa    = __expf(m_run - m_new);
        const float p     = __expf(x - m_new);
        const float ls    = wave_sum_bcast(p);
        l_run = l_run * aa + ls;
        m_run = m_new;
        o.x *= aa; o.y *= aa; o.z *= aa; o.w *= aa;

        __syncthreads();   // A: all waves done reading ksm; vsm free (prev PV < prev D)

        // 4. write v_ch to LDS (implicit vmcnt); issue k_{ch+1} loads
        #pragma unroll
        for (int it = 0; it < F4C; ++it) {
            const int f   = tid + 256 * it;
            const int row = f >> 6;
            const int c4  = f & 63;
            *(float4*)&vsm[row][c4 << 2] = vreg[it];
        }
        if (ch + 1 < NCH) {
            #pragma unroll
            for (int it = 0; it < F4C; ++it) {
                const int f   = tid + 256 * it;
                const int row = f >> 6;
                const int c4  = f & 63;
                kreg[it] = *(const float4*)(kn + (size_t)(d0 + DC + row) * S_ + (c4 << 2));
            }
        }
        __syncthreads();   // B: vsm ready

        // 6. PV: o[c][squad] += sum_d p[d] * v[d][squad]  (k_{ch+1} in flight)
        #pragma unroll
        for (int dd = 0; dd < DC; ++dd) {
            const float pd = __int_as_float(__builtin_amdgcn_readlane(__float_as_int(p), dd));
            const float4 vv = *(const float4*)&vsm[dd][lane << 2]; // row-broadcast pattern
            o.x += pd * vv.x; o.y += pd * vv.y;
            o.z += pd * vv.z; o.w += pd * vv.w;
        }

        // 8. write k_{ch+1} (ksm reads ended before A; implicit vmcnt wait)
        if (ch + 1 < NCH) {
            #pragma unroll
            for (int it = 0; it < F4C; ++it) {
                const int f   = tid + 256 * it;
                const int row = f >> 6;
                const int c4  = f & 63;
                *(float4*)&ksm[row][c4 << 2] = kreg[it];
            }
        }
        __syncthreads();   // D: ksm ready for next chunk's logits
    }

    // ---- epilogue: normalize and write out (coalesced 1 KB per wave) ----
    const float inv = 1.f / l_run;
    float4 r;
    r.x = o.x * inv; r.y = o.y * inv; r.z = o.z * inv; r.w = o.w * inv;
    *(float4*)(out + ((size_t)n * C_ + c0 + w) * S_ + (lane << 2)) = r;
}

extern "C" void kernel_launch(void* const* d_in, const int* in_sizes, int n_in,
                              void* d_out, int out_size, void* d_ws, size_t ws_size,
                              hipStream_t stream) {
    const float* q = (const float*)d_in[0];
    const float* k = (const float*)d_in[1];
    const float* v = (const float*)d_in[2];
    float* out = (float*)d_out;
    (void)d_ws; (void)ws_size;   // workspace unused: no split, no combine

    laplace_attn_fused<<<dim3(N_ * (C_ / TC)), dim3(256), 0, stream>>>(q, k, v, out);
}

// Round 4
// 108.712 us; speedup vs baseline: 1.5247x; 1.5247x over previous
//
#include <hip/hip_runtime.h>

// Laplace attention: N=2, C=512, S=256, fp32.
// weights[n,c,d] = softmax_d( -sum_s |k[n,d,s]-q[n,c,s]| / 2 )
// out[n,c,s] = sum_d weights[n,c,d] * v[n,d,s]
//
// Round-8: fused, single-shot softmax, occupancy-first.
// Round-7 post-mortem: FETCH fixed (50MB) but Occupancy 10%/VALUBusy 12% --
// 4 waves/CU (1/SIMD) latency-bound. This round: 256 blocks x 512 threads
// (8 waves/CU, 2/SIMD), thread<->d bijection:
//  - Thread tid owns d-row=tid for ALL 4 q-rows (tile 4c x 1d): each k
//    float4 from LDS feeds 32 VALU; q via UNIFORM SCALAR loads (c0, ch, s4
//    all block-uniform -> s_load, costs no LDS/VMEM-vector bandwidth).
//  - k streamed via LDS in 8 s-chunks, [512][36] (stride==4 mod 32: the
//    rotation class that measured 0 bank conflicts in round-7), reg-
//    prefetch one chunk ahead, 2 barriers/chunk.
//  - Single-shot block softmax over all 512 logits (wt[512][4] in LDS,
//    per-component DPP wave reduce + 8-wave LDS reduce); weights pre-
//    normalized by 1/l so PV needs no epilogue scale.
//  - PV: wave w owns d in [64w,64w+64); v read from GLOBAL (row reads are
//    inherently coalesced 1KB/wave-instr, L2-resident); 8 wave-partials
//    combined via LDS aliased over ksm (k is dead by then).
//  - XCD mapping: n = b&1 with round-robin dispatch -> each XCD touches
//    exactly one n's k/v/q panels (~2.5MB < 4MB L2).
// Workspace untouched (the 256MiB harness poison + its writeback is an
// ambient ~40us cost we cannot control from the kernel).

constexpr int N_  = 2;
constexpr int C_  = 512;
constexpr int S_  = 256;
constexpr int TC  = 4;            // q rows per block
constexpr int NT  = 512;          // threads per block
constexpr int NW  = NT / 64;      // 8 waves
constexpr int SC  = 32;           // s-chunk
constexpr int NCH = S_ / SC;      // 8 chunks
constexpr int KST = SC + 4;       // 36 floats: ==4 mod 32, 16B-aligned rows
constexpr int KF4 = C_ * (SC / 4) / NT;  // float4 per thread per k-chunk = 8

// ---- DPP wave-reduce helpers ----
template <int CTRL, int ROW_MASK>
__device__ __forceinline__ float dpp_add(float x) {
    int yi = __builtin_amdgcn_update_dpp(0, __float_as_int(x), CTRL, ROW_MASK, 0xf, true);
    return x + __int_as_float(yi);
}
template <int CTRL, int ROW_MASK>
__device__ __forceinline__ float dpp_max(float x) {
    int yi = __builtin_amdgcn_update_dpp(__float_as_int(x), __float_as_int(x), CTRL, ROW_MASK, 0xf, false);
    return fmaxf(x, __int_as_float(yi));
}
__device__ __forceinline__ float wave_sum_bcast(float x) {
    x = dpp_add<0x111, 0xf>(x);   // row_shr:1
    x = dpp_add<0x112, 0xf>(x);   // row_shr:2
    x = dpp_add<0x114, 0xf>(x);   // row_shr:4
    x = dpp_add<0x118, 0xf>(x);   // row_shr:8
    x = dpp_add<0x142, 0xa>(x);   // row_bcast15
    x = dpp_add<0x143, 0xc>(x);   // row_bcast31 -> lane63 = total
    return __int_as_float(__builtin_amdgcn_readlane(__float_as_int(x), 63));
}
__device__ __forceinline__ float wave_max_bcast(float x) {
    x = dpp_max<0x111, 0xf>(x);
    x = dpp_max<0x112, 0xf>(x);
    x = dpp_max<0x114, 0xf>(x);
    x = dpp_max<0x118, 0xf>(x);
    x = dpp_max<0x142, 0xa>(x);
    x = dpp_max<0x143, 0xc>(x);
    return __int_as_float(__builtin_amdgcn_readlane(__float_as_int(x), 63));
}
__device__ __forceinline__ void fma4(float4& a, const float s, const float4& v) {
    a.x += s * v.x; a.y += s * v.y; a.z += s * v.z; a.w += s * v.w;
}

__global__ __launch_bounds__(NT, 1)
void laplace_attn_fused(const float* __restrict__ qg,
                        const float* __restrict__ kg,
                        const float* __restrict__ vg,
                        float* __restrict__ out) {
    // LDS: ksm 73728 + wt 8192 + red 256 = 82.2 KB -> 1 block/CU (8 waves)
    __shared__ __align__(16) float ksm[C_][KST];
    __shared__ __align__(16) float wt[C_][TC];
    __shared__ float4 red1[NW];
    __shared__ float4 red2[NW];

    // PV partial buffer aliases ksm (k is dead after the last logits chunk):
    // po[w][c][quad] : 8*4*64*16B = 32 KB < 73.7 KB.
    float4 (*po)[TC][S_ / 4] = (float4 (*)[TC][S_ / 4])&ksm[0][0];

    const int b    = blockIdx.x;
    const int n    = b & 1;               // XCD x sees only n = x&1
    const int c0   = (b >> 1) * TC;
    const int tid  = threadIdx.x;
    const int w    = tid >> 6;
    const int lane = tid & 63;

    const float* kn = kg + (size_t)n * C_ * S_;
    const float* vn = vg + (size_t)n * C_ * S_;
    const float* qn = qg + ((size_t)n * C_ + c0) * S_;   // 4 rows, block-uniform

    // ---- prologue: stage k chunk 0 ----
    float4 kreg[KF4];
    #pragma unroll
    for (int it = 0; it < KF4; ++it) {
        const int f   = tid + NT * it;    // 0..4095 float4 slots
        const int row = f >> 3;           // 8 float4 per row-chunk
        const int c4  = f & 7;
        kreg[it] = *(const float4*)(kn + (size_t)row * S_ + (c4 << 2));
    }
    #pragma unroll
    for (int it = 0; it < KF4; ++it) {
        const int f   = tid + NT * it;
        *(float4*)&ksm[f >> 3][(f & 7) << 2] = kreg[it];
    }
    __syncthreads();

    // ---- logits: thread owns d = tid; dist[c] over s-chunks ----
    float dist0 = 0.f, dist1 = 0.f, dist2 = 0.f, dist3 = 0.f;

    for (int ch = 0; ch < NCH; ++ch) {
        // prefetch next chunk into regs (latency hides under compute)
        if (ch + 1 < NCH) {
            const float* kc = kn + (ch + 1) * SC;
            #pragma unroll
            for (int it = 0; it < KF4; ++it) {
                const int f   = tid + NT * it;
                const int row = f >> 3;
                const int c4  = f & 7;
                kreg[it] = *(const float4*)(kc + (size_t)row * S_ + (c4 << 2));
            }
        }
        // q pointers: fully block-uniform -> scalar loads (SMEM pipe)
        const float* q0 = qn + 0 * S_ + ch * SC;
        const float* q1 = qn + 1 * S_ + ch * SC;
        const float* q2 = qn + 2 * S_ + ch * SC;
        const float* q3 = qn + 3 * S_ + ch * SC;
        #pragma unroll
        for (int s4 = 0; s4 < SC / 4; ++s4) {
            const float4 kf = *(const float4*)&ksm[tid][s4 << 2];
            const int s = s4 << 2;
            dist0 += (fabsf(kf.x - q0[s]) + fabsf(kf.y - q0[s + 1]))
                   + (fabsf(kf.z - q0[s + 2]) + fabsf(kf.w - q0[s + 3]));
            dist1 += (fabsf(kf.x - q1[s]) + fabsf(kf.y - q1[s + 1]))
                   + (fabsf(kf.z - q1[s + 2]) + fabsf(kf.w - q1[s + 3]));
            dist2 += (fabsf(kf.x - q2[s]) + fabsf(kf.y - q2[s + 1]))
                   + (fabsf(kf.z - q2[s + 2]) + fabsf(kf.w - q2[s + 3]));
            dist3 += (fabsf(kf.x - q3[s]) + fabsf(kf.y - q3[s + 1]))
                   + (fabsf(kf.z - q3[s + 2]) + fabsf(kf.w - q3[s + 3]));
        }
        __syncthreads();                 // all waves done reading ksm chunk
        if (ch + 1 < NCH) {
            #pragma unroll
            for (int it = 0; it < KF4; ++it) {
                const int f = tid + NT * it;
                *(float4*)&ksm[f >> 3][(f & 7) << 2] = kreg[it];
            }
            __syncthreads();             // chunk ch+1 ready
        }
    }

    // ---- block softmax over d (single-shot, 4 components = 4 q-rows) ----
    float4 x;
    x.x = -0.5f * dist0; x.y = -0.5f * dist1;
    x.z = -0.5f * dist2; x.w = -0.5f * dist3;

    float4 mx;
    mx.x = wave_max_bcast(x.x); mx.y = wave_max_bcast(x.y);
    mx.z = wave_max_bcast(x.z); mx.w = wave_max_bcast(x.w);
    if (lane == 0) red1[w] = mx;
    __syncthreads();
    float4 M = red1[0];
    #pragma unroll
    for (int u = 1; u < NW; ++u) {
        const float4 r = red1[u];
        M.x = fmaxf(M.x, r.x); M.y = fmaxf(M.y, r.y);
        M.z = fmaxf(M.z, r.z); M.w = fmaxf(M.w, r.w);
    }

    float4 p;
    p.x = __expf(x.x - M.x); p.y = __expf(x.y - M.y);
    p.z = __expf(x.z - M.z); p.w = __expf(x.w - M.w);

    float4 sv;
    sv.x = wave_sum_bcast(p.x); sv.y = wave_sum_bcast(p.y);
    sv.z = wave_sum_bcast(p.z); sv.w = wave_sum_bcast(p.w);
    if (lane == 0) red2[w] = sv;
    __syncthreads();
    float4 L = red2[0];
    #pragma unroll
    for (int u = 1; u < NW; ++u) {
        const float4 r = red2[u];
        L.x += r.x; L.y += r.y; L.z += r.z; L.w += r.w;
    }
    // pre-normalize weights: PV output needs no epilogue scale
    p.x *= (1.f / L.x); p.y *= (1.f / L.y);
    p.z *= (1.f / L.z); p.w *= (1.f / L.w);
    *(float4*)&wt[tid][0] = p;
    __syncthreads();                     // wt complete; ksm dead -> po usable

    // ---- PV: wave w owns d in [64w, 64w+64); v from global (coalesced) ----
    float4 o0 = make_float4(0.f, 0.f, 0.f, 0.f), o1 = o0, o2 = o0, o3 = o0;
    const int dbase = w << 6;
    #pragma unroll 8
    for (int dd = 0; dd < 64; ++dd) {
        const int d = dbase + dd;
        const float4 vv = *(const float4*)(vn + (size_t)d * S_ + (lane << 2));
        const float4 pw = *(const float4*)&wt[d][0];   // uniform broadcast
        fma4(o0, pw.x, vv); fma4(o1, pw.y, vv);
        fma4(o2, pw.z, vv); fma4(o3, pw.w, vv);
    }
    po[w][0][lane] = o0; po[w][1][lane] = o1;
    po[w][2][lane] = o2; po[w][3][lane] = o3;
    __syncthreads();

    // ---- combine 8 wave-partials, write out ----
    if (tid < TC * 64) {
        const int c    = tid >> 6;
        const int quad = tid & 63;
        float4 s = po[0][c][quad];
        #pragma unroll
        for (int u = 1; u < NW; ++u) {
            const float4 r = po[u][c][quad];
            s.x += r.x; s.y += r.y; s.z += r.z; s.w += r.w;
        }
        *(float4*)(out + ((size_t)n * C_ + c0 + c) * S_ + (quad << 2)) = s;
    }
}

extern "C" void kernel_launch(void* const* d_in, const int* in_sizes, int n_in,
                              void* d_out, int out_size, void* d_ws, size_t ws_size,
                              hipStream_t stream) {
    const float* q = (const float*)d_in[0];
    const float* k = (const float*)d_in[1];
    const float* v = (const float*)d_in[2];
    float* out = (float*)d_out;
    (void)d_ws; (void)ws_size;   // workspace unused

    laplace_attn_fused<<<dim3(N_ * (C_ / TC)), dim3(NT), 0, stream>>>(q, k, v, out);
}

// Round 5
// 82.280 us; speedup vs baseline: 2.0145x; 1.3212x over previous
//
#include <hip/hip_runtime.h>

// Laplace attention: N=2, C=512, S=256, fp32.
// weights[n,c,d] = softmax_d( -sum_s |k[n,d,s]-q[n,c,s]| / 2 )
// out[n,c,s] = sum_d weights[n,c,d] * v[n,d,s]
//
// Round-9: no-LDS-staging streaming design.
// Round-8 post-mortem: FETCH fixed (5MB, L2-resident) but 1.06e7 LDS bank-
// conflict cycles (~17us) from ksm's per-lane-row reads (stride 36) and
// 8-float4-row staging writes, + 17 barriers at only 2 waves/SIMD.
// Realization: the x4 c-row reuse of k lives in REGISTERS (thread owns d,
// keeps 4 running distances), so LDS k-staging buys nothing -- k crosses
// L2->CU exactly once per block either way. Hence:
//  - k: streamed per-thread from global (L2-hot; each 64B line is consumed
//    entirely by one thread across 4 consecutive float4 loads -> no
//    over-fetch). No ksm, no staging writes, no per-chunk barriers.
//  - q: scalar-pipe loads (block-uniform addresses), batched per 32-s chunk.
//  - LDS only: wt[512][4] (contiguous float4 writes / uniform broadcast
//    reads) + po[8][4][64] float4 (contiguous per-instruction) + red --
//    all patterns that measured ZERO conflicts in round-7. 40.8 KB.
//  - 4 barriers total (red1, red2, wt, po).
//  - Same XCD mapping (n = b&1 -> each XCD's L2 holds one n's 2.5MB).
// Floor: each block pulls k+v = 2MB from L2; 256 blocks -> 512MB at
// ~34.5TB/s = ~15us. VALU ~ 6us. Target main ~20-28us.
// (The ~40us 256MiB workspace-poison fill is harness-side, ambient.)

constexpr int N_  = 2;
constexpr int C_  = 512;
constexpr int S_  = 256;
constexpr int TC  = 4;            // q rows per block
constexpr int NT  = 512;          // threads per block (8 waves, thread<->d bijection)
constexpr int NW  = NT / 64;      // 8 waves
constexpr int SC  = 32;           // s-chunk (q scalar batching)
constexpr int NCH = S_ / SC;      // 8 chunks

// ---- DPP wave-reduce helpers ----
template <int CTRL, int ROW_MASK>
__device__ __forceinline__ float dpp_add(float x) {
    int yi = __builtin_amdgcn_update_dpp(0, __float_as_int(x), CTRL, ROW_MASK, 0xf, true);
    return x + __int_as_float(yi);
}
template <int CTRL, int ROW_MASK>
__device__ __forceinline__ float dpp_max(float x) {
    int yi = __builtin_amdgcn_update_dpp(__float_as_int(x), __float_as_int(x), CTRL, ROW_MASK, 0xf, false);
    return fmaxf(x, __int_as_float(yi));
}
__device__ __forceinline__ float wave_sum_bcast(float x) {
    x = dpp_add<0x111, 0xf>(x);   // row_shr:1
    x = dpp_add<0x112, 0xf>(x);   // row_shr:2
    x = dpp_add<0x114, 0xf>(x);   // row_shr:4
    x = dpp_add<0x118, 0xf>(x);   // row_shr:8
    x = dpp_add<0x142, 0xa>(x);   // row_bcast15
    x = dpp_add<0x143, 0xc>(x);   // row_bcast31 -> lane63 = total
    return __int_as_float(__builtin_amdgcn_readlane(__float_as_int(x), 63));
}
__device__ __forceinline__ float wave_max_bcast(float x) {
    x = dpp_max<0x111, 0xf>(x);
    x = dpp_max<0x112, 0xf>(x);
    x = dpp_max<0x114, 0xf>(x);
    x = dpp_max<0x118, 0xf>(x);
    x = dpp_max<0x142, 0xa>(x);
    x = dpp_max<0x143, 0xc>(x);
    return __int_as_float(__builtin_amdgcn_readlane(__float_as_int(x), 63));
}
__device__ __forceinline__ void fma4(float4& a, const float s, const float4& v) {
    a.x += s * v.x; a.y += s * v.y; a.z += s * v.z; a.w += s * v.w;
}

__global__ __launch_bounds__(NT, 1)
void laplace_attn_fused(const float* __restrict__ qg,
                        const float* __restrict__ kg,
                        const float* __restrict__ vg,
                        float* __restrict__ out) {
    // LDS: wt 8KB + po 32KB + red 256B = 40.8 KB. All access patterns are
    // contiguous-per-instruction or uniform-broadcast (round-7: 0 conflicts).
    __shared__ __align__(16) float  wt[C_][TC];
    __shared__ __align__(16) float4 po[NW][TC][S_ / 4];
    __shared__ float4 red1[NW];
    __shared__ float4 red2[NW];

    const int b    = blockIdx.x;
    const int n    = b & 1;               // XCD x sees only n = x&1
    const int c0   = (b >> 1) * TC;
    const int tid  = threadIdx.x;
    const int w    = tid >> 6;
    const int lane = tid & 63;

    const float* kn = kg + (size_t)n * C_ * S_;
    const float* vn = vg + (size_t)n * C_ * S_;
    const float* qn = qg + ((size_t)n * C_ + c0) * S_;   // 4 rows, block-uniform
    const float* kd = kn + (size_t)tid * S_;             // this thread's k row

    // ---- logits: thread owns d = tid; stream k[d] from global (L2-hot) ----
    float dist0 = 0.f, dist1 = 0.f, dist2 = 0.f, dist3 = 0.f;

    for (int ch = 0; ch < NCH; ++ch) {
        // q pointers: fully block-uniform -> scalar loads (SMEM pipe)
        const float* q0 = qn + 0 * S_ + ch * SC;
        const float* q1 = qn + 1 * S_ + ch * SC;
        const float* q2 = qn + 2 * S_ + ch * SC;
        const float* q3 = qn + 3 * S_ + ch * SC;
        const float* kc = kd + ch * SC;
        #pragma unroll
        for (int s4 = 0; s4 < SC / 4; ++s4) {
            const float4 kf = *(const float4*)(kc + (s4 << 2));
            const int s = s4 << 2;
            dist0 += (fabsf(kf.x - q0[s]) + fabsf(kf.y - q0[s + 1]))
                   + (fabsf(kf.z - q0[s + 2]) + fabsf(kf.w - q0[s + 3]));
            dist1 += (fabsf(kf.x - q1[s]) + fabsf(kf.y - q1[s + 1]))
                   + (fabsf(kf.z - q1[s + 2]) + fabsf(kf.w - q1[s + 3]));
            dist2 += (fabsf(kf.x - q2[s]) + fabsf(kf.y - q2[s + 1]))
                   + (fabsf(kf.z - q2[s + 2]) + fabsf(kf.w - q2[s + 3]));
            dist3 += (fabsf(kf.x - q3[s]) + fabsf(kf.y - q3[s + 1]))
                   + (fabsf(kf.z - q3[s + 2]) + fabsf(kf.w - q3[s + 3]));
        }
    }

    // ---- block softmax over d (single-shot, 4 components = 4 q-rows) ----
    float4 x;
    x.x = -0.5f * dist0; x.y = -0.5f * dist1;
    x.z = -0.5f * dist2; x.w = -0.5f * dist3;

    float4 mx;
    mx.x = wave_max_bcast(x.x); mx.y = wave_max_bcast(x.y);
    mx.z = wave_max_bcast(x.z); mx.w = wave_max_bcast(x.w);
    if (lane == 0) red1[w] = mx;
    __syncthreads();
    float4 M = red1[0];
    #pragma unroll
    for (int u = 1; u < NW; ++u) {
        const float4 r = red1[u];
        M.x = fmaxf(M.x, r.x); M.y = fmaxf(M.y, r.y);
        M.z = fmaxf(M.z, r.z); M.w = fmaxf(M.w, r.w);
    }

    float4 p;
    p.x = __expf(x.x - M.x); p.y = __expf(x.y - M.y);
    p.z = __expf(x.z - M.z); p.w = __expf(x.w - M.w);

    float4 sv;
    sv.x = wave_sum_bcast(p.x); sv.y = wave_sum_bcast(p.y);
    sv.z = wave_sum_bcast(p.z); sv.w = wave_sum_bcast(p.w);
    if (lane == 0) red2[w] = sv;
    __syncthreads();
    float4 L = red2[0];
    #pragma unroll
    for (int u = 1; u < NW; ++u) {
        const float4 r = red2[u];
        L.x += r.x; L.y += r.y; L.z += r.z; L.w += r.w;
    }
    // pre-normalize weights: PV output needs no epilogue scale
    p.x *= (1.f / L.x); p.y *= (1.f / L.y);
    p.z *= (1.f / L.z); p.w *= (1.f / L.w);
    *(float4*)&wt[tid][0] = p;            // contiguous 16B/thread
    __syncthreads();

    // ---- PV: wave w owns d in [64w, 64w+64); v from global (coalesced) ----
    float4 o0 = make_float4(0.f, 0.f, 0.f, 0.f), o1 = o0, o2 = o0, o3 = o0;
    const int dbase = w << 6;
    #pragma unroll 8
    for (int dd = 0; dd < 64; ++dd) {
        const int d = dbase + dd;
        const float4 vv = *(const float4*)(vn + (size_t)d * S_ + (lane << 2));
        const float4 pw = *(const float4*)&wt[d][0];   // uniform broadcast
        fma4(o0, pw.x, vv); fma4(o1, pw.y, vv);
        fma4(o2, pw.z, vv); fma4(o3, pw.w, vv);
    }
    po[w][0][lane] = o0; po[w][1][lane] = o1;
    po[w][2][lane] = o2; po[w][3][lane] = o3;
    __syncthreads();

    // ---- combine 8 wave-partials, write out ----
    if (tid < TC * 64) {
        const int c    = tid >> 6;
        const int quad = tid & 63;
        float4 s = po[0][c][quad];
        #pragma unroll
        for (int u = 1; u < NW; ++u) {
            const float4 r = po[u][c][quad];
            s.x += r.x; s.y += r.y; s.z += r.z; s.w += r.w;
        }
        *(float4*)(out + ((size_t)n * C_ + c0 + c) * S_ + (quad << 2)) = s;
    }
}

extern "C" void kernel_launch(void* const* d_in, const int* in_sizes, int n_in,
                              void* d_out, int out_size, void* d_ws, size_t ws_size,
                              hipStream_t stream) {
    const float* q = (const float*)d_in[0];
    const float* k = (const float*)d_in[1];
    const float* v = (const float*)d_in[2];
    float* out = (float*)d_out;
    (void)d_ws; (void)ws_size;   // workspace unused

    laplace_attn_fused<<<dim3(N_ * (C_ / TC)), dim3(NT), 0, stream>>>(q, k, v, out);
}

// Round 6
// 79.755 us; speedup vs baseline: 2.0782x; 1.0317x over previous
//
#include <hip/hip_runtime.h>

// Laplace attention: N=2, C=512, S=256, fp32.
// weights[n,c,d] = softmax_d( -sum_s |k[n,d,s]-q[n,c,s]| / 2 )
// out[n,c,s] = sum_d weights[n,c,d] * v[n,d,s]
//
// Round-10: stall removal on the round-9 streaming skeleton.
// Round-9 estimate: main ~35us vs floors of L2 7.4us / VALU 3.4us ->
// stall-bound. Two stall sources identified:
//  1. q on the scalar pipe: 128 q floats/chunk > SGPR double-buffer budget
//     -> serial s_load/lgkmcnt bubbles inside the hot loop.
//     FIX: q staged once in LDS (4KB); logits read it via uniform-address
//     ds_read_b128 BROADCAST (0 conflicts by definition, ds-pipe latency
//     hidden by unrolled scheduling; scalar pipe freed).
//  2. k L1 line-splitting: lanes stride 1KB; each wave-load touched 64
//     lines consuming 16B each, reuse 3 iterations later -> L1 thrash.
//     FIX: s-loop in 64B-LINE GROUPS: 4 back-to-back dwordx4 per thread
//     cover exactly one k line -> MSHR-merged, one L2 access per line.
//  - Logits loop barrier-free (q read-only after 1 staging barrier);
//    #pragma unroll 4 lets the compiler pipeline k-lines deeply.
//  - Everything else (thread<->d bijection, single-shot softmax, global-v
//    PV, po wave-partial combine, n=b&1 XCD mapping) kept from round-9.
// Ambient: harness poisons the 256MiB workspace every iter (~41.6us fill
// at 80% HBM peak) -- unavoidable floor, workspace unused by us.

constexpr int N_  = 2;
constexpr int C_  = 512;
constexpr int S_  = 256;
constexpr int TC  = 4;            // q rows per block
constexpr int NT  = 512;          // threads per block (8 waves, thread<->d bijection)
constexpr int NW  = NT / 64;      // 8 waves
constexpr int NG  = S_ / 16;      // 16 s-line-groups (64B each)

// ---- DPP wave-reduce helpers ----
template <int CTRL, int ROW_MASK>
__device__ __forceinline__ float dpp_add(float x) {
    int yi = __builtin_amdgcn_update_dpp(0, __float_as_int(x), CTRL, ROW_MASK, 0xf, true);
    return x + __int_as_float(yi);
}
template <int CTRL, int ROW_MASK>
__device__ __forceinline__ float dpp_max(float x) {
    int yi = __builtin_amdgcn_update_dpp(__float_as_int(x), __float_as_int(x), CTRL, ROW_MASK, 0xf, false);
    return fmaxf(x, __int_as_float(yi));
}
__device__ __forceinline__ float wave_sum_bcast(float x) {
    x = dpp_add<0x111, 0xf>(x);   // row_shr:1
    x = dpp_add<0x112, 0xf>(x);   // row_shr:2
    x = dpp_add<0x114, 0xf>(x);   // row_shr:4
    x = dpp_add<0x118, 0xf>(x);   // row_shr:8
    x = dpp_add<0x142, 0xa>(x);   // row_bcast15
    x = dpp_add<0x143, 0xc>(x);   // row_bcast31 -> lane63 = total
    return __int_as_float(__builtin_amdgcn_readlane(__float_as_int(x), 63));
}
__device__ __forceinline__ float wave_max_bcast(float x) {
    x = dpp_max<0x111, 0xf>(x);
    x = dpp_max<0x112, 0xf>(x);
    x = dpp_max<0x114, 0xf>(x);
    x = dpp_max<0x118, 0xf>(x);
    x = dpp_max<0x142, 0xa>(x);
    x = dpp_max<0x143, 0xc>(x);
    return __int_as_float(__builtin_amdgcn_readlane(__float_as_int(x), 63));
}
__device__ __forceinline__ void fma4(float4& a, const float s, const float4& v) {
    a.x += s * v.x; a.y += s * v.y; a.z += s * v.z; a.w += s * v.w;
}
__device__ __forceinline__ float l1_16(const float4& k0, const float4& k1,
                                       const float4& k2, const float4& k3,
                                       const float4& qa, const float4& qb,
                                       const float4& qc, const float4& qd) {
    const float t0 = (fabsf(k0.x - qa.x) + fabsf(k0.y - qa.y))
                   + (fabsf(k0.z - qa.z) + fabsf(k0.w - qa.w));
    const float t1 = (fabsf(k1.x - qb.x) + fabsf(k1.y - qb.y))
                   + (fabsf(k1.z - qb.z) + fabsf(k1.w - qb.w));
    const float t2 = (fabsf(k2.x - qc.x) + fabsf(k2.y - qc.y))
                   + (fabsf(k2.z - qc.z) + fabsf(k2.w - qc.w));
    const float t3 = (fabsf(k3.x - qd.x) + fabsf(k3.y - qd.y))
                   + (fabsf(k3.z - qd.z) + fabsf(k3.w - qd.w));
    return (t0 + t1) + (t2 + t3);
}

__global__ __launch_bounds__(NT, 1)
void laplace_attn_fused(const float* __restrict__ qg,
                        const float* __restrict__ kg,
                        const float* __restrict__ vg,
                        float* __restrict__ out) {
    // LDS: qs 4KB + wt 8KB + po 32KB + red 256B = 44.3 KB.
    // qs/wt reads: uniform-address broadcast (0 conflicts).
    // qs/wt/po writes + po reads: lane-contiguous (free 2-way).
    __shared__ __align__(16) float  qs[TC][S_];
    __shared__ __align__(16) float  wt[C_][TC];
    __shared__ __align__(16) float4 po[NW][TC][S_ / 4];
    __shared__ float4 red1[NW];
    __shared__ float4 red2[NW];

    const int b    = blockIdx.x;
    const int n    = b & 1;               // XCD x sees only n = x&1
    const int c0   = (b >> 1) * TC;
    const int tid  = threadIdx.x;
    const int w    = tid >> 6;
    const int lane = tid & 63;

    const float* kn = kg + (size_t)n * C_ * S_;
    const float* vn = vg + (size_t)n * C_ * S_;
    const float* qn = qg + ((size_t)n * C_ + c0) * S_;

    // ---- stage q (4 rows = 256 float4) into LDS, lane-contiguous ----
    if (tid < TC * (S_ / 4)) {
        const int row = tid >> 6;
        const int col = (tid & 63) << 2;
        *(float4*)&qs[row][col] = *(const float4*)(qn + (size_t)row * S_ + col);
    }
    __syncthreads();

    // ---- logits: thread owns d = tid; k in 64B-line groups from global ----
    const float4* kdv = (const float4*)(kn + (size_t)tid * S_);
    float dist0 = 0.f, dist1 = 0.f, dist2 = 0.f, dist3 = 0.f;

    #pragma unroll 4
    for (int g = 0; g < NG; ++g) {
        // one full 64B line of this thread's k row (MSHR-merged)
        const float4 k0 = kdv[4 * g + 0];
        const float4 k1 = kdv[4 * g + 1];
        const float4 k2 = kdv[4 * g + 2];
        const float4 k3 = kdv[4 * g + 3];
        const int s = g << 4;
        {   // c = 0
            const float4 qa = *(const float4*)&qs[0][s + 0];
            const float4 qb = *(const float4*)&qs[0][s + 4];
            const float4 qc = *(const float4*)&qs[0][s + 8];
            const float4 qd = *(const float4*)&qs[0][s + 12];
            dist0 += l1_16(k0, k1, k2, k3, qa, qb, qc, qd);
        }
        {   // c = 1
            const float4 qa = *(const float4*)&qs[1][s + 0];
            const float4 qb = *(const float4*)&qs[1][s + 4];
            const float4 qc = *(const float4*)&qs[1][s + 8];
            const float4 qd = *(const float4*)&qs[1][s + 12];
            dist1 += l1_16(k0, k1, k2, k3, qa, qb, qc, qd);
        }
        {   // c = 2
            const float4 qa = *(const float4*)&qs[2][s + 0];
            const float4 qb = *(const float4*)&qs[2][s + 4];
            const float4 qc = *(const float4*)&qs[2][s + 8];
            const float4 qd = *(const float4*)&qs[2][s + 12];
            dist2 += l1_16(k0, k1, k2, k3, qa, qb, qc, qd);
        }
        {   // c = 3
            const float4 qa = *(const float4*)&qs[3][s + 0];
            const float4 qb = *(const float4*)&qs[3][s + 4];
            const float4 qc = *(const float4*)&qs[3][s + 8];
            const float4 qd = *(const float4*)&qs[3][s + 12];
            dist3 += l1_16(k0, k1, k2, k3, qa, qb, qc, qd);
        }
    }

    // ---- block softmax over d (single-shot, 4 components = 4 q-rows) ----
    float4 x;
    x.x = -0.5f * dist0; x.y = -0.5f * dist1;
    x.z = -0.5f * dist2; x.w = -0.5f * dist3;

    float4 mx;
    mx.x = wave_max_bcast(x.x); mx.y = wave_max_bcast(x.y);
    mx.z = wave_max_bcast(x.z); mx.w = wave_max_bcast(x.w);
    if (lane == 0) red1[w] = mx;
    __syncthreads();
    float4 M = red1[0];
    #pragma unroll
    for (int u = 1; u < NW; ++u) {
        const float4 r = red1[u];
        M.x = fmaxf(M.x, r.x); M.y = fmaxf(M.y, r.y);
        M.z = fmaxf(M.z, r.z); M.w = fmaxf(M.w, r.w);
    }

    float4 p;
    p.x = __expf(x.x - M.x); p.y = __expf(x.y - M.y);
    p.z = __expf(x.z - M.z); p.w = __expf(x.w - M.w);

    float4 sv;
    sv.x = wave_sum_bcast(p.x); sv.y = wave_sum_bcast(p.y);
    sv.z = wave_sum_bcast(p.z); sv.w = wave_sum_bcast(p.w);
    if (lane == 0) red2[w] = sv;
    __syncthreads();
    float4 L = red2[0];
    #pragma unroll
    for (int u = 1; u < NW; ++u) {
        const float4 r = red2[u];
        L.x += r.x; L.y += r.y; L.z += r.z; L.w += r.w;
    }
    // pre-normalize weights: PV output needs no epilogue scale
    p.x *= (1.f / L.x); p.y *= (1.f / L.y);
    p.z *= (1.f / L.z); p.w *= (1.f / L.w);
    *(float4*)&wt[tid][0] = p;            // contiguous 16B/thread
    __syncthreads();

    // ---- PV: wave w owns d in [64w, 64w+64); v from global (coalesced) ----
    float4 o0 = make_float4(0.f, 0.f, 0.f, 0.f), o1 = o0, o2 = o0, o3 = o0;
    const int dbase = w << 6;
    #pragma unroll 8
    for (int dd = 0; dd < 64; ++dd) {
        const int d = dbase + dd;
        const float4 vv = *(const float4*)(vn + (size_t)d * S_ + (lane << 2));
        const float4 pw = *(const float4*)&wt[d][0];   // uniform broadcast
        fma4(o0, pw.x, vv); fma4(o1, pw.y, vv);
        fma4(o2, pw.z, vv); fma4(o3, pw.w, vv);
    }
    po[w][0][lane] = o0; po[w][1][lane] = o1;
    po[w][2][lane] = o2; po[w][3][lane] = o3;
    __syncthreads();

    // ---- combine 8 wave-partials, write out ----
    if (tid < TC * 64) {
        const int c    = tid >> 6;
        const int quad = tid & 63;
        float4 s = po[0][c][quad];
        #pragma unroll
        for (int u = 1; u < NW; ++u) {
            const float4 r = po[u][c][quad];
            s.x += r.x; s.y += r.y; s.z += r.z; s.w += r.w;
        }
        *(float4*)(out + ((size_t)n * C_ + c0 + c) * S_ + (quad << 2)) = s;
    }
}

extern "C" void kernel_launch(void* const* d_in, const int* in_sizes, int n_in,
                              void* d_out, int out_size, void* d_ws, size_t ws_size,
                              hipStream_t stream) {
    const float* q = (const float*)d_in[0];
    const float* k = (const float*)d_in[1];
    const float* v = (const float*)d_in[2];
    float* out = (float*)d_out;
    (void)d_ws; (void)ws_size;   // workspace unused

    laplace_attn_fused<<<dim3(N_ * (C_ / TC)), dim3(NT), 0, stream>>>(q, k, v, out);
}